// Round 2
// baseline (185.193 us; speedup 1.0000x reference)
//
#include <hip/hip_runtime.h>
#include <stdint.h>

typedef __attribute__((ext_vector_type(8))) short bf16x8;
typedef __attribute__((ext_vector_type(4))) float f32x4;
typedef unsigned short ushort_t;

#define B_ 8
#define S_ 2048
#define D_ 2048
#define E_ 8
#define J_ 128

static __device__ __forceinline__ unsigned short f2bf(float f) {
  union { float f; uint32_t u; } v; v.f = f;
  uint32_t u = v.u;
  return (unsigned short)((u + 0x7FFFu + ((u >> 16) & 1u)) >> 16);
}

#define GLL16(gsrc, ldst)                                                        \
  __builtin_amdgcn_global_load_lds(                                              \
      (const __attribute__((address_space(1))) void*)(gsrc),                     \
      (__attribute__((address_space(3))) void*)(ldst), 16, 0, 0)

// K0: build pre-swizzled bf16 operand layouts + init logits with biases.
// Ag: [kt=0..31][j=0..127][c=0..7] 16B chunks; chunk c holds A[j][kt*64 + 8*(c^(j&7)) .. +7]
// Bg: [d=0..2047][c=0..15] chunks; chunk c holds BcT[d][8*(c^(d&7)) .. +7] (j-space)
__global__ void k_prep(const float* __restrict__ lA, const float* __restrict__ lB,
                       ushort_t* __restrict__ Ag, ushort_t* __restrict__ Bg,
                       const float* __restrict__ tb, const float* __restrict__ mb,
                       const int* __restrict__ task_p, const int* __restrict__ mode_p,
                       float* __restrict__ logits) {
  int gid = blockIdx.x * blockDim.x + threadIdx.x;
  int stride = gridDim.x * blockDim.x;
  for (int o = gid; o < 32 * 128 * 8 * 8; o += stride) {
    int wi = o & 7, ch = o >> 3;
    int kt = ch >> 10, i = ch & 1023;
    int j = i >> 3, c = i & 7;
    int d = kt * 64 + (((c ^ j) & 7) << 3) + wi;
    Ag[o] = f2bf(lA[j * D_ + d]);
  }
  for (int o = gid; o < D_ * J_; o += stride) {
    int d = o >> 7, idx = o & 127;
    int c = idx >> 3, wi = idx & 7;
    int jj = ((c ^ (d & 7)) << 3) + wi;   // c in 0..15, xor low 3 bits
    int e = jj >> 4, r = jj & 15;
    Bg[o] = f2bf(lB[(size_t)e * (D_ * 16) + d * 16 + r]);
  }
  if (gid < 64) {
    int e = gid & 7;
    logits[gid] = tb[task_p[0] * E_ + e] + mb[mode_p[0] * E_ + e];
  }
}

// K1: mid[b][s][j] = x[b][s][:] . A[j][:]  (all 128 j, bf16 MFMA), fused logit partials.
__global__ __launch_bounds__(256) void k_mid(const float* __restrict__ x,
    const ushort_t* __restrict__ Ag, const float* __restrict__ gw,
    float* __restrict__ mid, float* __restrict__ logits) {
  __shared__ float Xs[2][2048];        // 32 rows x 16 chunks(16B), chunk-swizzled
  __shared__ ushort_t Ab[2][8192];     // 128 rows x 8 chunks(16B), chunk-swizzled
  __shared__ float tmpPool[2][4][64];
  const int tid = threadIdx.x;
  const int w = tid >> 6, lane = tid & 63;
  const int lm = lane & 15, g = lane >> 4;
  const int b = blockIdx.y, s0 = blockIdx.x * 32;
  const int row16 = (w & 1) * 16, jbase = (w >> 1) * 64;
  const float* xb = x + ((size_t)(b * S_ + s0)) * D_;

  f32x4 acc[4] = {};
  float lp[8] = {0.f, 0.f, 0.f, 0.f, 0.f, 0.f, 0.f, 0.f};
  float gwv[8];

  auto stageX = [&](int buf, int kt) {
    const int d0 = kt * 64;
#pragma unroll
    for (int c = 0; c < 2; ++c) {
      int i = c * 256 + w * 64 + lane;
      int row = i >> 4, ch = i & 15;
      const float* src = xb + (size_t)row * D_ + d0 + (((ch ^ row) & 15 & (15 ^ 8) ? 0 : 0) , ((ch ^ (row & 7)) << 2));
      GLL16(src, &Xs[buf][(c * 256 + w * 64) * 4]);
    }
  };
  auto stageA = [&](int buf, int kt) {
#pragma unroll
    for (int c = 0; c < 4; ++c) {
      const ushort_t* src = Ag + (size_t)kt * 8192 + (size_t)(c * 256 + w * 64 + lane) * 8;
      GLL16(src, &Ab[buf][(c * 256 + w * 64) * 8]);
    }
  };

  stageX(0, 0); stageA(0, 0);
  __syncthreads();

  for (int t = 0; t < 32; ++t) {
    const int cb = t & 1;
    if (t + 1 < 32) { stageX(cb ^ 1, t + 1); stageA(cb ^ 1, t + 1); }
    if (w == 0 && t > 0) {
      int pb = (t - 1) & 1;
      float cs = tmpPool[pb][0][lane] + tmpPool[pb][1][lane] +
                 tmpPool[pb][2][lane] + tmpPool[pb][3][lane];
#pragma unroll
      for (int e = 0; e < 8; ++e) lp[e] += cs * gwv[e];
    }
    if (w == 0) {
      int d = t * 64 + lane;
#pragma unroll
      for (int e = 0; e < 8; ++e) gwv[e] = gw[e * D_ + d];
    }
    // MFMA on current buffer
#pragma unroll
    for (int ks = 0; ks < 2; ++ks) {
      const int r = row16 + lm;
      const int c0 = ks * 8 + g * 2;
      float4 v0 = *(const float4*)&Xs[cb][r * 64 + ((c0 ^ (r & 7)) << 2)];
      float4 v1 = *(const float4*)&Xs[cb][r * 64 + (((c0 + 1) ^ (r & 7)) << 2)];
      bf16x8 xf;
      xf[0] = (short)f2bf(v0.x); xf[1] = (short)f2bf(v0.y);
      xf[2] = (short)f2bf(v0.z); xf[3] = (short)f2bf(v0.w);
      xf[4] = (short)f2bf(v1.x); xf[5] = (short)f2bf(v1.y);
      xf[6] = (short)f2bf(v1.z); xf[7] = (short)f2bf(v1.w);
#pragma unroll
      for (int nn = 0; nn < 4; ++nn) {
        int jr = jbase + nn * 16 + lm;
        bf16x8 af = *(const bf16x8*)&Ab[cb][jr * 64 + (((ks * 4 + g) ^ (jr & 7)) << 3)];
        acc[nn] = __builtin_amdgcn_mfma_f32_16x16x32_bf16(af, xf, acc[nn], 0, 0, 0);
      }
    }
    // pooling partial: thread (w, lane) sums rows w*8..w*8+7 at column `lane`
    {
      float s = 0.f;
#pragma unroll
      for (int i = 0; i < 8; ++i) {
        int r = w * 8 + i;
        s += Xs[cb][r * 64 + (((lane >> 2) ^ (r & 7)) << 2) + (lane & 3)];
      }
      tmpPool[cb][w][lane] = s;
    }
    __syncthreads();
  }

  // epilogue: last pool merge + cross-lane reduce + atomic logits
  if (w == 0) {
    int pb = 31 & 1;
    float cs = tmpPool[pb][0][lane] + tmpPool[pb][1][lane] +
               tmpPool[pb][2][lane] + tmpPool[pb][3][lane];
#pragma unroll
    for (int e = 0; e < 8; ++e) lp[e] += cs * gwv[e];
#pragma unroll
    for (int e = 0; e < 8; ++e) {
      float v = lp[e];
      v += __shfl_xor(v, 32); v += __shfl_xor(v, 16); v += __shfl_xor(v, 8);
      v += __shfl_xor(v, 4);  v += __shfl_xor(v, 2);  v += __shfl_xor(v, 1);
      if (lane == 0) atomicAdd(&logits[b * E_ + e], v * (1.f / (float)S_));
    }
  }

  // mid store: float4 along j (operand swap put j in the row dim)
  float* mp = mid + ((size_t)(b * S_ + s0 + row16 + lm)) * J_ + jbase;
#pragma unroll
  for (int nn = 0; nn < 4; ++nn)
    *(f32x4*)&mp[nn * 16 + g * 4] = acc[nn];
}

// K2: out[b][s][d] = sum_j coeff[b][j]*mid[b][s][j]*BcT[d][j]; coeff from logits in-block.
__global__ __launch_bounds__(256) void k_comb(const float* __restrict__ mid,
    const float* __restrict__ logits, const ushort_t* __restrict__ Bg,
    float* __restrict__ out) {
  __shared__ ushort_t Bt[16384];  // 128 d-rows x 16 chunks(16B), swizzled
  const int bid = blockIdx.x;
  const int xcd = bid & 7, slot = bid >> 3;
  const int n = slot >> 5, mbl = slot & 31;
  const int mb = xcd + (mbl << 3);
  const int m = mb >> 3, b = mb & 7;
  const int tid = threadIdx.x, w = tid >> 6, lane = tid & 63;
  const int lm = lane & 15, g = lane >> 4;

  // router combine weights (uniform per block)
  float lg[8];
#pragma unroll
  for (int e = 0; e < 8; ++e) lg[e] = logits[b * E_ + e];
  int i1 = 0;
#pragma unroll
  for (int e = 1; e < 8; ++e) if (lg[e] > lg[i1]) i1 = e;
  int i2 = (i1 == 0) ? 1 : 0;
#pragma unroll
  for (int e = 0; e < 8; ++e) if (e != i1 && lg[e] > lg[i2]) i2 = e;
  float ex = __expf(lg[i2] - lg[i1]);
  float w1 = 1.f / (1.f + ex), w2 = ex * w1;

  // stage BcT slice (32KB) via async gload_lds
#pragma unroll
  for (int c = 0; c < 8; ++c) {
    const ushort_t* src = Bg + (size_t)n * 16384 + (size_t)(c * 256 + w * 64 + lane) * 8;
    GLL16(src, &Bt[(c * 256 + w * 64) * 8]);
  }

  // P-operand: global->reg, scale by coeff, convert; skip inactive expert pairs
  const float* mp = mid + ((size_t)(b * S_ + m * 64 + w * 16 + lm)) * J_;
  bf16x8 pf[4];
  bool actv[4];
#pragma unroll
  for (int ks = 0; ks < 4; ++ks) {
    const int e0 = 2 * ks, e1 = 2 * ks + 1;
    actv[ks] = (e0 == i1) | (e0 == i2) | (e1 == i1) | (e1 == i2);
    if (actv[ks]) {
      float4 u0 = *(const float4*)(mp + ks * 32 + g * 8);
      float4 u1 = *(const float4*)(mp + ks * 32 + g * 8 + 4);
      const int e = e0 + (g >> 1);
      const float cl = (e == i1) ? w1 : ((e == i2) ? w2 : 0.f);
      bf16x8 pw;
      pw[0] = (short)f2bf(u0.x * cl); pw[1] = (short)f2bf(u0.y * cl);
      pw[2] = (short)f2bf(u0.z * cl); pw[3] = (short)f2bf(u0.w * cl);
      pw[4] = (short)f2bf(u1.x * cl); pw[5] = (short)f2bf(u1.y * cl);
      pw[6] = (short)f2bf(u1.z * cl); pw[7] = (short)f2bf(u1.w * cl);
      pf[ks] = pw;
    }
  }
  __syncthreads();

  f32x4 acc[8] = {};
#pragma unroll
  for (int nn = 0; nn < 8; ++nn) {
    const int dr = nn * 16 + lm;
#pragma unroll
    for (int ks = 0; ks < 4; ++ks) {
      if (actv[ks]) {
        bf16x8 af = *(const bf16x8*)&Bt[dr * 128 + (((ks * 4 + g) ^ (dr & 7)) << 3)];
        acc[nn] = __builtin_amdgcn_mfma_f32_16x16x32_bf16(af, pf[ks], acc[nn], 0, 0, 0);
      }
    }
  }

  // float4 stores along d (operand swap put d in the row dim)
  float* op = out + ((size_t)(b * S_ + m * 64 + w * 16 + lm)) * D_ + n * 128;
#pragma unroll
  for (int nn = 0; nn < 8; ++nn)
    *(f32x4*)&op[nn * 16 + g * 4] = acc[nn];
}

extern "C" void kernel_launch(void* const* d_in, const int* in_sizes, int n_in,
                              void* d_out, int out_size, void* d_ws, size_t ws_size,
                              hipStream_t stream) {
  const float* x   = (const float*)d_in[0];
  const float* gw  = (const float*)d_in[1];
  const float* tb  = (const float*)d_in[2];
  const float* mb  = (const float*)d_in[3];
  const float* lA  = (const float*)d_in[4];
  const float* lB  = (const float*)d_in[5];
  const int* task_p = (const int*)d_in[6];
  const int* mode_p = (const int*)d_in[7];
  float* out = (float*)d_out;
  char* ws = (char*)d_ws;
  float* mid          = (float*)ws;                        // 8,388,608 B
  ushort_t* Ag        = (ushort_t*)(ws + 8388608);         //   524,288 B
  ushort_t* Bg        = (ushort_t*)(ws + 8912896);         //   524,288 B
  float* logits       = (float*)(ws + 9437184);            //       256 B

  hipLaunchKernelGGL(k_prep, dim3(256), dim3(256), 0, stream,
                     lA, lB, Ag, Bg, tb, mb, task_p, mode_p, logits);
  hipLaunchKernelGGL(k_mid, dim3(64, 8), dim3(256), 0, stream, x, Ag, gw, mid, logits);
  hipLaunchKernelGGL(k_comb, dim3(4096), dim3(256), 0, stream, mid, logits, Bg, out);
}

// Round 3
// 156.918 us; speedup vs baseline: 1.1802x; 1.1802x over previous
//
#include <hip/hip_runtime.h>
#include <stdint.h>

typedef __attribute__((ext_vector_type(8))) short bf16x8;
typedef __attribute__((ext_vector_type(4))) float f32x4;
typedef unsigned short ushort_t;

#define B_ 8
#define S_ 2048
#define D_ 2048
#define E_ 8
#define J_ 128

static __device__ __forceinline__ unsigned short f2bf(float f) {
  union { float f; uint32_t u; } v; v.f = f;
  uint32_t u = v.u;
  return (unsigned short)((u + 0x7FFFu + ((u >> 16) & 1u)) >> 16);
}
static __device__ __forceinline__ float bf2f(ushort_t h) {
  union { uint32_t u; float f; } v; v.u = ((uint32_t)h) << 16;
  return v.f;
}

// K0: Ag[j][d] = bf16(lora_A) (straight convert; j = e*16+r),
//     Bg[d][j] = bf16(lora_B[e][d][r]) with j = e*16+r,
//     logits[b*8+e] = task_bias + mode_bias (atomic-accumulated by k_mid).
__global__ void k_prep(const float* __restrict__ lA, const float* __restrict__ lB,
                       ushort_t* __restrict__ Ag, ushort_t* __restrict__ Bg,
                       const float* __restrict__ tb, const float* __restrict__ mb,
                       const int* __restrict__ task_p, const int* __restrict__ mode_p,
                       float* __restrict__ logits) {
  int gid = blockIdx.x * blockDim.x + threadIdx.x;
  int stride = gridDim.x * blockDim.x;
  for (int i = gid; i < (J_ * D_) / 4; i += stride) {
    float4 v = ((const float4*)lA)[i];
    uint2 pk;
    pk.x = (uint32_t)f2bf(v.x) | ((uint32_t)f2bf(v.y) << 16);
    pk.y = (uint32_t)f2bf(v.z) | ((uint32_t)f2bf(v.w) << 16);
    ((uint2*)Ag)[i] = pk;
  }
  for (int o4 = gid; o4 < (D_ * J_) / 4; o4 += stride) {
    int j4 = o4 & 31, dd = o4 >> 5;
    int e = j4 >> 2, r0 = (j4 & 3) * 4;
    float4 v = *(const float4*)(lB + ((size_t)e * D_ + dd) * 16 + r0);
    uint2 pk;
    pk.x = (uint32_t)f2bf(v.x) | ((uint32_t)f2bf(v.y) << 16);
    pk.y = (uint32_t)f2bf(v.z) | ((uint32_t)f2bf(v.w) << 16);
    ((uint2*)Bg)[o4] = pk;
  }
  if (gid < B_ * E_) {
    int e = gid & 7;
    logits[gid] = tb[task_p[0] * E_ + e] + mb[mode_p[0] * E_ + e];
  }
}

// K1: mid[b][s][j] = x[b][s][:] . A[j][:] for all 128 j, + fused logit partials.
// 16 s-rows per block, grid (128, 8). 4 waves each own 32 j-columns.
__global__ __launch_bounds__(256) void k_mid(const float* __restrict__ x,
    const ushort_t* __restrict__ Ag, const float* __restrict__ gw,
    float* __restrict__ mid, float* __restrict__ logits) {
  __shared__ ushort_t Xb[2][16][72];   // bf16 x tile, +8 pad
  __shared__ float tmpP[2][4][64];
  const int tid = threadIdx.x;
  const int w = tid >> 6, lane = tid & 63;
  const int lm = lane & 15, g = lane >> 4;
  const int b = blockIdx.y, s0 = blockIdx.x * 16;
  const float* xb = x + ((size_t)(b * S_ + s0)) * D_;
  const int sr = tid >> 4, sc = (tid & 15) * 4;   // stage mapping: row, col-group

  f32x4 acc[2] = {};
  float lp0 = 0.f, lp1 = 0.f;
  const ushort_t* abase = Ag + ((size_t)(w * 32 + lm)) * D_ + g * 8;

  auto stageX = [&](int buf, float4 v) {
    uint2 pk;
    pk.x = (uint32_t)f2bf(v.x) | ((uint32_t)f2bf(v.y) << 16);
    pk.y = (uint32_t)f2bf(v.z) | ((uint32_t)f2bf(v.w) << 16);
    *(uint2*)&Xb[buf][sr][sc] = pk;
  };

  // prologue: tile 0
  float4 xv = *(const float4*)(xb + (size_t)sr * D_ + sc);
  bf16x8 afc0 = *(const bf16x8*)(abase);
  bf16x8 afc1 = *(const bf16x8*)(abase + 32);
  bf16x8 afc2 = *(const bf16x8*)(abase + 16 * D_);
  bf16x8 afc3 = *(const bf16x8*)(abase + 16 * D_ + 32);
  stageX(0, xv);
  __syncthreads();

  float gwc0 = 0.f, gwc1 = 0.f;
  for (int t = 0; t < 32; ++t) {
    const int cb = t & 1;
    float4 xn;
    bf16x8 afn0, afn1, afn2, afn3;
    if (t + 1 < 32) {
      const int d1 = (t + 1) * 64;
      xn = *(const float4*)(xb + (size_t)sr * D_ + d1 + sc);   // HBM, issued early
      afn0 = *(const bf16x8*)(abase + d1);
      afn1 = *(const bf16x8*)(abase + d1 + 32);
      afn2 = *(const bf16x8*)(abase + 16 * D_ + d1);
      afn3 = *(const bf16x8*)(abase + 16 * D_ + d1 + 32);
    }
    // fold pool partials of tile t-1 into logit partials
    if (t > 0) {
      const int pb = cb ^ 1;
      float cs = tmpP[pb][0][lane] + tmpP[pb][1][lane] +
                 tmpP[pb][2][lane] + tmpP[pb][3][lane];
      lp0 += cs * gwc0;
      lp1 += cs * gwc1;
    }
    gwc0 = gw[(size_t)(2 * w) * D_ + t * 64 + lane];
    gwc1 = gw[(size_t)(2 * w + 1) * D_ + t * 64 + lane];
    // MFMA on current buffer
    bf16x8 xf0 = *(const bf16x8*)&Xb[cb][lm][g * 8];
    bf16x8 xf1 = *(const bf16x8*)&Xb[cb][lm][32 + g * 8];
    acc[0] = __builtin_amdgcn_mfma_f32_16x16x32_bf16(afc0, xf0, acc[0], 0, 0, 0);
    acc[0] = __builtin_amdgcn_mfma_f32_16x16x32_bf16(afc1, xf1, acc[0], 0, 0, 0);
    acc[1] = __builtin_amdgcn_mfma_f32_16x16x32_bf16(afc2, xf0, acc[1], 0, 0, 0);
    acc[1] = __builtin_amdgcn_mfma_f32_16x16x32_bf16(afc3, xf1, acc[1], 0, 0, 0);
    // pool partial: thread (w, lane) sums rows w*4..w*4+3 at column lane
    {
      float s = bf2f(Xb[cb][w * 4 + 0][lane]) + bf2f(Xb[cb][w * 4 + 1][lane]) +
                bf2f(Xb[cb][w * 4 + 2][lane]) + bf2f(Xb[cb][w * 4 + 3][lane]);
      tmpP[cb][w][lane] = s;
    }
    __syncthreads();   // all reads of buf cb done
    if (t + 1 < 32) {
      stageX(cb ^ 1, xn);
      afc0 = afn0; afc1 = afn1; afc2 = afn2; afc3 = afn3;
    }
    __syncthreads();   // writes to cb^1 visible
  }
  // epilogue: fold tile 31
  {
    float cs = tmpP[1][0][lane] + tmpP[1][1][lane] +
               tmpP[1][2][lane] + tmpP[1][3][lane];
    lp0 += cs * gwc0;
    lp1 += cs * gwc1;
  }
#pragma unroll
  for (int off = 32; off; off >>= 1) {
    lp0 += __shfl_xor(lp0, off);
    lp1 += __shfl_xor(lp1, off);
  }
  if (lane == 0) {
    atomicAdd(&logits[b * E_ + 2 * w],     lp0 * (1.f / (float)S_));
    atomicAdd(&logits[b * E_ + 2 * w + 1], lp1 * (1.f / (float)S_));
  }
  // mid store: float4 along j (C rows = j)
  float* mp = mid + ((size_t)(b * S_ + s0 + lm)) * J_ + w * 32;
  *(f32x4*)&mp[g * 4] = acc[0];
  *(f32x4*)&mp[16 + g * 4] = acc[1];
}

// K2: out[b][s][d] = sum over 2 active experts' 32 j of coeff*mid*B.
// grid (16 n-fastest, 32 m, 8 b); K=32; 8KB LDS; store-BW-bound.
__global__ __launch_bounds__(256) void k_comb(const float* __restrict__ mid,
    const float* __restrict__ logits, const ushort_t* __restrict__ Bg,
    float* __restrict__ out) {
  __shared__ ushort_t Bt[128][40];   // 2 active experts x 16 j, +8 pad
  const int n = blockIdx.x, m = blockIdx.y, b = blockIdx.z;
  const int tid = threadIdx.x, w = tid >> 6, lane = tid & 63;
  const int lm = lane & 15, g = lane >> 4;

  // router (uniform per block)
  float lg[8];
#pragma unroll
  for (int e = 0; e < 8; ++e) lg[e] = logits[b * E_ + e];
  int i1 = 0;
#pragma unroll
  for (int e = 1; e < 8; ++e) if (lg[e] > lg[i1]) i1 = e;
  int i2 = (i1 == 0) ? 1 : 0;
#pragma unroll
  for (int e = 0; e < 8; ++e) if (e != i1 && lg[e] > lg[i2]) i2 = e;
  float ex = __expf(lg[i2] - lg[i1]);
  float w1 = 1.f / (1.f + ex), w2 = ex * w1;

  // stage active-expert B slice: 512 chunks of 16B
#pragma unroll
  for (int c = 0; c < 2; ++c) {
    int ci = c * 256 + tid;
    int d = ci >> 2, sub = ci & 3;
    int e = (sub & 2) ? i2 : i1;
    const ushort_t* src = Bg + ((size_t)(n * 128 + d)) * J_ + e * 16 + (sub & 1) * 8;
    *(bf16x8*)&Bt[d][sub * 8] = *(const bf16x8*)src;
  }

  // P fragment: active 32 j-columns of mid, scaled, bf16
  const int srow = m * 64 + w * 16 + lm;
  const float* mp = mid + ((size_t)(b * S_ + srow)) * J_;
  const int jw = (g < 2) ? (i1 * 16 + g * 8) : (i2 * 16 + (g - 2) * 8);
  const float cl = (g < 2) ? w1 : w2;
  float4 u0 = *(const float4*)(mp + jw);
  float4 u1 = *(const float4*)(mp + jw + 4);
  bf16x8 pf;
  pf[0] = (short)f2bf(u0.x * cl); pf[1] = (short)f2bf(u0.y * cl);
  pf[2] = (short)f2bf(u0.z * cl); pf[3] = (short)f2bf(u0.w * cl);
  pf[4] = (short)f2bf(u1.x * cl); pf[5] = (short)f2bf(u1.y * cl);
  pf[6] = (short)f2bf(u1.z * cl); pf[7] = (short)f2bf(u1.w * cl);
  __syncthreads();

  f32x4 acc[8] = {};
#pragma unroll
  for (int nn = 0; nn < 8; ++nn) {
    bf16x8 af = *(const bf16x8*)&Bt[nn * 16 + lm][g * 8];
    acc[nn] = __builtin_amdgcn_mfma_f32_16x16x32_bf16(af, pf, acc[nn], 0, 0, 0);
  }

  float* op = out + ((size_t)(b * S_ + srow)) * D_ + n * 128;
#pragma unroll
  for (int nn = 0; nn < 8; ++nn)
    *(f32x4*)&op[nn * 16 + g * 4] = acc[nn];
}

extern "C" void kernel_launch(void* const* d_in, const int* in_sizes, int n_in,
                              void* d_out, int out_size, void* d_ws, size_t ws_size,
                              hipStream_t stream) {
  const float* x    = (const float*)d_in[0];
  const float* gw   = (const float*)d_in[1];
  const float* tb   = (const float*)d_in[2];
  const float* mb   = (const float*)d_in[3];
  const float* lA   = (const float*)d_in[4];
  const float* lB   = (const float*)d_in[5];
  const int* task_p = (const int*)d_in[6];
  const int* mode_p = (const int*)d_in[7];
  float* out = (float*)d_out;
  char* ws = (char*)d_ws;
  float* mid    = (float*)ws;                    // 8,388,608 B
  ushort_t* Ag  = (ushort_t*)(ws + 8388608);     //   524,288 B
  ushort_t* Bg  = (ushort_t*)(ws + 8912896);     //   524,288 B
  float* logits = (float*)(ws + 9437184);        //       256 B

  hipLaunchKernelGGL(k_prep, dim3(256), dim3(256), 0, stream,
                     lA, lB, Ag, Bg, tb, mb, task_p, mode_p, logits);
  hipLaunchKernelGGL(k_mid, dim3(128, 8), dim3(256), 0, stream, x, Ag, gw, mid, logits);
  hipLaunchKernelGGL(k_comb, dim3(16, 32, 8), dim3(256), 0, stream, mid, logits, Bg, out);
}

// Round 5
// 93.990 us; speedup vs baseline: 1.9703x; 1.6695x over previous
//
#include <hip/hip_runtime.h>
#include <stdint.h>

typedef __attribute__((ext_vector_type(8))) short bf16x8;
typedef __attribute__((ext_vector_type(4))) float f32x4;
typedef unsigned short ushort_t;

#define B_ 8
#define S_ 2048
#define D_ 2048
#define E_ 8
#define J_ 128

static __device__ __forceinline__ unsigned short f2bf(float f) {
  union { float f; uint32_t u; } v; v.f = f;
  uint32_t u = v.u;
  return (unsigned short)((u + 0x7FFFu + ((u >> 16) & 1u)) >> 16);
}
static __device__ __forceinline__ float bf2f(ushort_t h) {
  union { uint32_t u; float f; } v; v.u = ((uint32_t)h) << 16;
  return v.f;
}

#define GLL16(gsrc, ldst)                                                        \
  __builtin_amdgcn_global_load_lds(                                              \
      (const __attribute__((address_space(1))) void*)(gsrc),                     \
      (__attribute__((address_space(3))) void*)(ldst), 16, 0, 0)

// K0: Ag = chunk-swizzled bf16 lora_A for gload_lds staging:
//   Ag[kt][j][c][0..7] = bf16(lA[j][kt*64 + ((c ^ (j&7))*8) .. +7])
// Bg[d][j] = bf16(lora_B[e][d][r]), j = e*16+r (linear, for reg-staged k_comb).
__global__ void k_prep(const float* __restrict__ lA, const float* __restrict__ lB,
                       ushort_t* __restrict__ Ag, ushort_t* __restrict__ Bg) {
  int gid = blockIdx.x * blockDim.x + threadIdx.x;
  int stride = gridDim.x * blockDim.x;
  for (int o = gid; o < 32 * 128 * 8 * 8; o += stride) {
    int wi = o & 7, ch = o >> 3;
    int kt = ch >> 10, i = ch & 1023;
    int j = i >> 3, c = i & 7;
    int d = kt * 64 + (((c ^ j) & 7) << 3) + wi;
    Ag[o] = f2bf(lA[j * D_ + d]);
  }
  for (int o4 = gid; o4 < (D_ * J_) / 4; o4 += stride) {
    int j4 = o4 & 31, dd = o4 >> 5;
    int e = j4 >> 2, r0 = (j4 & 3) * 4;
    float4 v = *(const float4*)(lB + ((size_t)e * D_ + dd) * 16 + r0);
    uint2 pk;
    pk.x = (uint32_t)f2bf(v.x) | ((uint32_t)f2bf(v.y) << 16);
    pk.y = (uint32_t)f2bf(v.z) | ((uint32_t)f2bf(v.w) << 16);
    ((uint2*)Bg)[o4] = pk;
  }
}

// K1: midb[b][s][j] (bf16) = x[b][s][:] . A[j][:], plus per-block logit partials
// written to a private slot (deterministic; no atomics).
__global__ __launch_bounds__(256) void k_mid(const float* __restrict__ x,
    const ushort_t* __restrict__ Ag, const float* __restrict__ gw,
    ushort_t* __restrict__ midb, float* __restrict__ lpart) {
  __shared__ float Xs[2][2048];        // 32 rows x 16 chunks(16B) fp32, chunk-swizzled
  __shared__ ushort_t Ab[2][8192];     // 128 rows x 8 chunks(16B) bf16, chunk-swizzled
  __shared__ float tmpP[2][4][64];
  const int tid = threadIdx.x;
  const int w = tid >> 6, lane = tid & 63;
  const int lm = lane & 15, g = lane >> 4;
  const int b = blockIdx.y, s0 = blockIdx.x * 32;
  const int row16 = (w & 1) * 16, jbase = (w >> 1) * 64;
  const float* xb = x + ((size_t)(b * S_ + s0)) * D_;

  f32x4 acc[4] = {};
  float lp0 = 0.f, lp1 = 0.f;
  float gwc0 = 0.f, gwc1 = 0.f;
  const float* gw0 = gw + (size_t)(2 * w) * D_;
  const float* gw1 = gw + (size_t)(2 * w + 1) * D_;

  auto stageX = [&](int buf, int kt) {
    const int d0 = kt * 64;
#pragma unroll
    for (int c = 0; c < 2; ++c) {
      int i = c * 256 + w * 64 + lane;
      int row = i >> 4, ch = i & 15;
      const float* src = xb + (size_t)row * D_ + d0 + ((ch ^ (row & 7)) << 2);
      GLL16(src, &Xs[buf][(c * 256 + w * 64) * 4]);
    }
  };
  auto stageA = [&](int buf, int kt) {
#pragma unroll
    for (int c = 0; c < 4; ++c) {
      const ushort_t* src = Ag + (size_t)kt * 8192 + (size_t)(c * 256 + w * 64 + lane) * 8;
      GLL16(src, &Ab[buf][(c * 256 + w * 64) * 8]);
    }
  };

  stageX(0, 0); stageA(0, 0);
  __syncthreads();

  for (int t = 0; t < 32; ++t) {
    const int cb = t & 1;
    if (t + 1 < 32) { stageX(cb ^ 1, t + 1); stageA(cb ^ 1, t + 1); }
    // fold tile t-1 pool partials into logit partials (each wave: experts 2w, 2w+1)
    if (t > 0) {
      const int pb = cb ^ 1;
      float cs = tmpP[pb][0][lane] + tmpP[pb][1][lane] +
                 tmpP[pb][2][lane] + tmpP[pb][3][lane];
      lp0 += cs * gwc0;
      lp1 += cs * gwc1;
    }
    gwc0 = gw0[t * 64 + lane];
    gwc1 = gw1[t * 64 + lane];
    // MFMA on current buffer
    const int r = row16 + lm;
#pragma unroll
    for (int ks = 0; ks < 2; ++ks) {
      const int c0 = ks * 8 + g * 2;
      float4 v0 = *(const float4*)&Xs[cb][r * 64 + ((c0 ^ (r & 7)) << 2)];
      float4 v1 = *(const float4*)&Xs[cb][r * 64 + (((c0 + 1) ^ (r & 7)) << 2)];
      bf16x8 xf;
      xf[0] = (short)f2bf(v0.x); xf[1] = (short)f2bf(v0.y);
      xf[2] = (short)f2bf(v0.z); xf[3] = (short)f2bf(v0.w);
      xf[4] = (short)f2bf(v1.x); xf[5] = (short)f2bf(v1.y);
      xf[6] = (short)f2bf(v1.z); xf[7] = (short)f2bf(v1.w);
#pragma unroll
      for (int nn = 0; nn < 4; ++nn) {
        int jr = jbase + nn * 16 + lm;
        bf16x8 af = *(const bf16x8*)&Ab[cb][jr * 64 + (((ks * 4 + g) ^ (jr & 7)) << 3)];
        acc[nn] = __builtin_amdgcn_mfma_f32_16x16x32_bf16(af, xf, acc[nn], 0, 0, 0);
      }
    }
    // pool partial: thread (w, lane) sums rows w*8..w*8+7 at logical column `lane`
    {
      float s = 0.f;
#pragma unroll
      for (int i = 0; i < 8; ++i) {
        int rr = w * 8 + i;
        s += Xs[cb][rr * 64 + (((lane >> 2) ^ (rr & 7)) << 2) + (lane & 3)];
      }
      tmpP[cb][w][lane] = s;
    }
    __syncthreads();
  }
  // epilogue: fold tile 31 (parity 1)
  {
    float cs = tmpP[1][0][lane] + tmpP[1][1][lane] +
               tmpP[1][2][lane] + tmpP[1][3][lane];
    lp0 += cs * gwc0;
    lp1 += cs * gwc1;
  }
#pragma unroll
  for (int off = 32; off; off >>= 1) {
    lp0 += __shfl_xor(lp0, off);
    lp1 += __shfl_xor(lp1, off);
  }
  if (lane == 0) {
    float* lp = lpart + ((size_t)(b * 64 + blockIdx.x)) * 8;
    lp[2 * w] = lp0;
    lp[2 * w + 1] = lp1;
  }
  // mid store: bf16, 8B per lane along j (C rows = j, cols = s)
  ushort_t* mp = midb + ((size_t)(b * S_ + s0 + row16 + lm)) * J_ + jbase;
#pragma unroll
  for (int nn = 0; nn < 4; ++nn) {
    uint2 pk;
    pk.x = (uint32_t)f2bf(acc[nn][0]) | ((uint32_t)f2bf(acc[nn][1]) << 16);
    pk.y = (uint32_t)f2bf(acc[nn][2]) | ((uint32_t)f2bf(acc[nn][3]) << 16);
    *(uint2*)&mp[nn * 16 + g * 4] = pk;
  }
}

// K1.5: deterministic router. Fixed-order sum of the 64 per-block partials,
// + biases, top-2, softmax -> rinfo[b] = {i1, i2, w1, w2}.
__global__ void k_router(const float* __restrict__ lpart,
                         const float* __restrict__ tb, const float* __restrict__ mb,
                         const int* __restrict__ task_p, const int* __restrict__ mode_p,
                         float* __restrict__ rinfo) {
  __shared__ float lg[64];
  const int t = threadIdx.x;           // 64 threads
  const int b = t >> 3, e = t & 7;
  float s = 0.f;
  for (int k = 0; k < 64; ++k) s += lpart[((size_t)(b * 64 + k)) * 8 + e];
  lg[t] = s * (1.f / (float)S_) + tb[task_p[0] * E_ + e] + mb[mode_p[0] * E_ + e];
  __syncthreads();
  if (t < B_) {
    float v[8];
#pragma unroll
    for (int e2 = 0; e2 < 8; ++e2) v[e2] = lg[t * 8 + e2];
    int i1 = 0;
#pragma unroll
    for (int e2 = 1; e2 < 8; ++e2) if (v[e2] > v[i1]) i1 = e2;
    int i2 = (i1 == 0) ? 1 : 0;
#pragma unroll
    for (int e2 = 0; e2 < 8; ++e2) if (e2 != i1 && v[e2] > v[i2]) i2 = e2;
    float ex = __expf(v[i2] - v[i1]);
    float w1 = 1.f / (1.f + ex), w2 = ex * w1;
    float4 r;
    r.x = (float)i1; r.y = (float)i2; r.z = w1; r.w = w2;
    ((float4*)rinfo)[t] = r;
  }
}

// K2: out[b][s][d] = sum over 2 active experts (K=32) of mid_bf16 * (coeff*B).
// Coeff folded into the Bt stage; P path is raw bf16 loads. grid (16 n, 32 m, 8 b).
__global__ __launch_bounds__(256) void k_comb(const ushort_t* __restrict__ midb,
    const float* __restrict__ rinfo, const ushort_t* __restrict__ Bg,
    float* __restrict__ out) {
  __shared__ ushort_t Bt[128][40];   // [d-row][2 experts x 16 j], +8 pad
  const int n = blockIdx.x, m = blockIdx.y, b = blockIdx.z;
  const int tid = threadIdx.x, w = tid >> 6, lane = tid & 63;
  const int lm = lane & 15, g = lane >> 4;

  const float4 ri = ((const float4*)rinfo)[b];
  const int i1 = (int)ri.x, i2 = (int)ri.y;
  const float w1 = ri.z, w2 = ri.w;

  // stage active-expert B slice, scaled by combine weight
#pragma unroll
  for (int c = 0; c < 2; ++c) {
    int ci = c * 256 + tid;
    int d = ci >> 2, sub = ci & 3;
    int e = (sub & 2) ? i2 : i1;
    float sc = (sub & 2) ? w2 : w1;
    bf16x8 bv = *(const bf16x8*)(Bg + ((size_t)(n * 128 + d)) * J_ + e * 16 + (sub & 1) * 8);
    bf16x8 bw;
#pragma unroll
    for (int i = 0; i < 8; ++i) bw[i] = (short)f2bf(bf2f((ushort_t)bv[i]) * sc);
    *(bf16x8*)&Bt[d][sub * 8] = bw;
  }

  // P fragment: raw bf16 mid loads of the active 32 j-columns
  const int srow = m * 64 + w * 16 + lm;
  const int jw = (g < 2) ? (i1 * 16 + g * 8) : (i2 * 16 + (g - 2) * 8);
  bf16x8 pf = *(const bf16x8*)&midb[((size_t)(b * S_ + srow)) * J_ + jw];
  __syncthreads();

  f32x4 acc[8] = {};
#pragma unroll
  for (int nn = 0; nn < 8; ++nn) {
    bf16x8 af = *(const bf16x8*)&Bt[nn * 16 + lm][g * 8];
    acc[nn] = __builtin_amdgcn_mfma_f32_16x16x32_bf16(af, pf, acc[nn], 0, 0, 0);
  }

  float* op = out + ((size_t)(b * S_ + srow)) * D_ + n * 128;
#pragma unroll
  for (int nn = 0; nn < 8; ++nn)
    *(f32x4*)&op[nn * 16 + g * 4] = acc[nn];
}

extern "C" void kernel_launch(void* const* d_in, const int* in_sizes, int n_in,
                              void* d_out, int out_size, void* d_ws, size_t ws_size,
                              hipStream_t stream) {
  const float* x    = (const float*)d_in[0];
  const float* gw   = (const float*)d_in[1];
  const float* tb   = (const float*)d_in[2];
  const float* mb   = (const float*)d_in[3];
  const float* lA   = (const float*)d_in[4];
  const float* lB   = (const float*)d_in[5];
  const int* task_p = (const int*)d_in[6];
  const int* mode_p = (const int*)d_in[7];
  float* out = (float*)d_out;
  char* ws = (char*)d_ws;
  ushort_t* midb  = (ushort_t*)ws;                 // 4,194,304 B
  ushort_t* Ag    = (ushort_t*)(ws + 4194304);     //   524,288 B
  ushort_t* Bg    = (ushort_t*)(ws + 4718592);     //   524,288 B
  float* lpart    = (float*)(ws + 5242880);        //    16,384 B
  float* rinfo    = (float*)(ws + 5259264);        //       128 B

  hipLaunchKernelGGL(k_prep, dim3(256), dim3(256), 0, stream, lA, lB, Ag, Bg);
  hipLaunchKernelGGL(k_mid, dim3(64, 8), dim3(256), 0, stream, x, Ag, gw, midb, lpart);
  hipLaunchKernelGGL(k_router, dim3(1), dim3(64), 0, stream,
                     lpart, tb, mb, task_p, mode_p, rinfo);
  hipLaunchKernelGGL(k_comb, dim3(16, 32, 8), dim3(256), 0, stream, midb, rinfo, Bg, out);
}

// Round 6
// 88.785 us; speedup vs baseline: 2.0859x; 1.0586x over previous
//
#include <hip/hip_runtime.h>
#include <stdint.h>

typedef __attribute__((ext_vector_type(8))) short bf16x8;
typedef __attribute__((ext_vector_type(4))) float f32x4;
typedef unsigned short ushort_t;

#define B_ 8
#define S_ 2048
#define D_ 2048
#define E_ 8
#define J_ 128

static __device__ __forceinline__ unsigned short f2bf(float f) {
  union { float f; uint32_t u; } v; v.f = f;
  uint32_t u = v.u;
  return (unsigned short)((u + 0x7FFFu + ((u >> 16) & 1u)) >> 16);
}
static __device__ __forceinline__ float bf2f(ushort_t h) {
  union { uint32_t u; float f; } v; v.u = ((uint32_t)h) << 16;
  return v.f;
}

#define GLL16(gsrc, ldst)                                                        \
  __builtin_amdgcn_global_load_lds(                                              \
      (const __attribute__((address_space(1))) void*)(gsrc),                     \
      (__attribute__((address_space(3))) void*)(ldst), 16, 0, 0)

// counted-vmcnt barrier: wait for all but N outstanding vmem ops, drain LDS ops
// for cross-wave tmpP/poolL visibility, then raw barrier. N is a literal.
#define VMBAR(N)                                                                 \
  asm volatile("s_waitcnt vmcnt(" #N ") lgkmcnt(0)\n\ts_barrier" ::: "memory")

// K0: Ag = chunk-swizzled bf16 lora_A for gload_lds staging:
//   Ag[kt][j][c][0..7] = bf16(lA[j][kt*64 + ((c ^ (j&7))*8) .. +7])
// Bg[d][j] = bf16(lora_B[e][d][r]), j = e*16+r (linear, for reg-staged k_comb).
__global__ void k_prep(const float* __restrict__ lA, const float* __restrict__ lB,
                       ushort_t* __restrict__ Ag, ushort_t* __restrict__ Bg) {
  int gid = blockIdx.x * blockDim.x + threadIdx.x;
  int stride = gridDim.x * blockDim.x;
  for (int o = gid; o < 32 * 128 * 8 * 8; o += stride) {
    int wi = o & 7, ch = o >> 3;
    int kt = ch >> 10, i = ch & 1023;
    int j = i >> 3, c = i & 7;
    int d = kt * 64 + (((c ^ j) & 7) << 3) + wi;
    Ag[o] = f2bf(lA[j * D_ + d]);
  }
  for (int o4 = gid; o4 < (D_ * J_) / 4; o4 += stride) {
    int j4 = o4 & 31, dd = o4 >> 5;
    int e = j4 >> 2, r0 = (j4 & 3) * 4;
    float4 v = *(const float4*)(lB + ((size_t)e * D_ + dd) * 16 + r0);
    uint2 pk;
    pk.x = (uint32_t)f2bf(v.x) | ((uint32_t)f2bf(v.y) << 16);
    pk.y = (uint32_t)f2bf(v.z) | ((uint32_t)f2bf(v.w) << 16);
    ((uint2*)Bg)[o4] = pk;
  }
}

// K1: midb[b][s][j] (bf16) = x[b][s][:] . A[j][:], + deterministic logit partials.
// Triple-buffered X / double-buffered A via global_load_lds; ONE raw barrier per
// iter with counted vmcnt(2) so prefetches span 2 iterations (never drain to 0).
__global__ __launch_bounds__(256) void k_mid(const float* __restrict__ x,
    const ushort_t* __restrict__ Ag, const float* __restrict__ gw,
    ushort_t* __restrict__ midb, float* __restrict__ lpart) {
  __shared__ float Xs[3][2048];        // 3 x 8KB fp32, chunk-swizzled
  __shared__ ushort_t Ab[2][8192];     // 2 x 16KB bf16, chunk-swizzled
  __shared__ float poolL[2048];        // 8KB: per-tile column sums
  __shared__ float tmpP[2][4][64];     // 2KB: per-wave pool partials
  const int tid = threadIdx.x;
  const int w = tid >> 6, lane = tid & 63;
  const int lm = lane & 15, g = lane >> 4;
  const int b = blockIdx.y, s0 = blockIdx.x * 32;
  const int row16 = (w & 1) * 16, jbase = (w >> 1) * 64;
  const float* xb = x + ((size_t)(b * S_ + s0)) * D_;

  f32x4 acc[4] = {};

  auto stageX = [&](int buf, int kt) {
    const int d0 = kt * 64;
#pragma unroll
    for (int c = 0; c < 2; ++c) {
      int i = c * 256 + w * 64 + lane;
      int row = i >> 4, ch = i & 15;
      const float* src = xb + (size_t)row * D_ + d0 + ((ch ^ (row & 7)) << 2);
      GLL16(src, &Xs[buf][(c * 256 + w * 64) * 4]);
    }
  };
  auto stageA = [&](int buf, int kt) {
#pragma unroll
    for (int c = 0; c < 4; ++c) {
      const ushort_t* src = Ag + (size_t)kt * 8192 + (size_t)(c * 256 + w * 64 + lane) * 8;
      GLL16(src, &Ab[buf][(c * 256 + w * 64) * 8]);
    }
  };
  auto computeTile = [&](int t, int xcb, int acb) {
    const int r = row16 + lm;
#pragma unroll
    for (int ks = 0; ks < 2; ++ks) {
      const int c0 = ks * 8 + g * 2;
      float4 v0 = *(const float4*)&Xs[xcb][r * 64 + ((c0 ^ (r & 7)) << 2)];
      float4 v1 = *(const float4*)&Xs[xcb][r * 64 + (((c0 + 1) ^ (r & 7)) << 2)];
      bf16x8 xf;
      xf[0] = (short)f2bf(v0.x); xf[1] = (short)f2bf(v0.y);
      xf[2] = (short)f2bf(v0.z); xf[3] = (short)f2bf(v0.w);
      xf[4] = (short)f2bf(v1.x); xf[5] = (short)f2bf(v1.y);
      xf[6] = (short)f2bf(v1.z); xf[7] = (short)f2bf(v1.w);
#pragma unroll
      for (int nn = 0; nn < 4; ++nn) {
        int jr = jbase + nn * 16 + lm;
        bf16x8 af = *(const bf16x8*)&Ab[acb][jr * 64 + (((ks * 4 + g) ^ (jr & 7)) << 3)];
        acc[nn] = __builtin_amdgcn_mfma_f32_16x16x32_bf16(af, xf, acc[nn], 0, 0, 0);
      }
    }
    // pool partial: thread (w, lane) sums rows w*8..w*8+7 at logical column lane
    float s = 0.f;
#pragma unroll
    for (int i = 0; i < 8; ++i) {
      int rr = w * 8 + i;
      s += Xs[xcb][rr * 64 + (((lane >> 2) ^ (rr & 7)) << 2) + (lane & 3)];
    }
    tmpP[t & 1][w][lane] = s;
  };
  auto foldTile = [&](int tau) {
    if (w == (tau & 3)) {
      float cs = tmpP[tau & 1][0][lane] + tmpP[tau & 1][1][lane] +
                 tmpP[tau & 1][2][lane] + tmpP[tau & 1][3][lane];
      poolL[tau * 64 + lane] = cs;
    }
  };

  // prologue: vmcnt issue order is part of the schedule: A(0):4, X(0):2, X(1):2
  stageA(0, 0);
  __builtin_amdgcn_sched_barrier(0);
  stageX(0, 0);
  __builtin_amdgcn_sched_barrier(0);
  stageX(1, 1);
  __builtin_amdgcn_sched_barrier(0);

  int xcb = 0, xsb = 2;
  for (int t = 0; t < 31; ++t) {
    VMBAR(2);   // A(t),X(t) landed; X(t+1)'s 2 loads stay in flight
    __builtin_amdgcn_sched_barrier(0);
    const int acb = t & 1;
    stageA(acb ^ 1, t + 1);          // 4 loads
    __builtin_amdgcn_sched_barrier(0);
    if (t + 2 < 32) stageX(xsb, t + 2);  // 2 loads
    __builtin_amdgcn_sched_barrier(0);
    if (t > 0) foldTile(t - 1);
    computeTile(t, xcb, acb);
    xcb = (xcb == 2) ? 0 : xcb + 1;
    xsb = (xsb == 2) ? 0 : xsb + 1;
  }
  // peeled last iteration: everything must land
  VMBAR(0);
  __builtin_amdgcn_sched_barrier(0);
  foldTile(30);
  computeTile(31, xcb, 1);

  // mid store (register-only source): bf16, 8B per lane along j
  ushort_t* mp = midb + ((size_t)(b * S_ + s0 + row16 + lm)) * J_ + jbase;
#pragma unroll
  for (int nn = 0; nn < 4; ++nn) {
    uint2 pk;
    pk.x = (uint32_t)f2bf(acc[nn][0]) | ((uint32_t)f2bf(acc[nn][1]) << 16);
    pk.y = (uint32_t)f2bf(acc[nn][2]) | ((uint32_t)f2bf(acc[nn][3]) << 16);
    *(uint2*)&mp[nn * 16 + g * 4] = pk;
  }

  __syncthreads();
  foldTile(31);
  __syncthreads();

  // epilogue: logits partial = poolL . gw for all 8 experts (fixed order)
  float lp[8] = {0.f, 0.f, 0.f, 0.f, 0.f, 0.f, 0.f, 0.f};
#pragma unroll
  for (int k = 0; k < 8; ++k) {
    float pv = poolL[k * 256 + tid];
#pragma unroll
    for (int e = 0; e < 8; ++e) lp[e] += pv * gw[(size_t)e * D_ + k * 256 + tid];
  }
#pragma unroll
  for (int e = 0; e < 8; ++e) {
    float v = lp[e];
    v += __shfl_xor(v, 32); v += __shfl_xor(v, 16); v += __shfl_xor(v, 8);
    v += __shfl_xor(v, 4);  v += __shfl_xor(v, 2);  v += __shfl_xor(v, 1);
    if (lane == 0) tmpP[0][w][e] = v;
  }
  __syncthreads();
  if (tid < 8) {
    float s = tmpP[0][0][tid] + tmpP[0][1][tid] + tmpP[0][2][tid] + tmpP[0][3][tid];
    lpart[((size_t)(b * 64 + blockIdx.x)) * 8 + tid] = s;
  }
}

// K1.5: deterministic router. Fixed-order sum of the 64 per-block partials,
// + biases, top-2, softmax -> rinfo[b] = {i1, i2, w1, w2}.
__global__ void k_router(const float* __restrict__ lpart,
                         const float* __restrict__ tb, const float* __restrict__ mb,
                         const int* __restrict__ task_p, const int* __restrict__ mode_p,
                         float* __restrict__ rinfo) {
  __shared__ float lg[64];
  const int t = threadIdx.x;           // 64 threads
  const int b = t >> 3, e = t & 7;
  float s = 0.f;
  for (int k = 0; k < 64; ++k) s += lpart[((size_t)(b * 64 + k)) * 8 + e];
  lg[t] = s * (1.f / (float)S_) + tb[task_p[0] * E_ + e] + mb[mode_p[0] * E_ + e];
  __syncthreads();
  if (t < B_) {
    float v[8];
#pragma unroll
    for (int e2 = 0; e2 < 8; ++e2) v[e2] = lg[t * 8 + e2];
    int i1 = 0;
#pragma unroll
    for (int e2 = 1; e2 < 8; ++e2) if (v[e2] > v[i1]) i1 = e2;
    int i2 = (i1 == 0) ? 1 : 0;
#pragma unroll
    for (int e2 = 0; e2 < 8; ++e2) if (e2 != i1 && v[e2] > v[i2]) i2 = e2;
    float ex = __expf(v[i2] - v[i1]);
    float w1 = 1.f / (1.f + ex), w2 = ex * w1;
    float4 r;
    r.x = (float)i1; r.y = (float)i2; r.z = w1; r.w = w2;
    ((float4*)rinfo)[t] = r;
  }
}

// K2: out[b][s][d] = sum over 2 active experts (K=32) of mid_bf16 * (coeff*B).
// Coeff folded into the Bt stage; P path is raw bf16 loads. grid (16 n, 32 m, 8 b).
__global__ __launch_bounds__(256) void k_comb(const ushort_t* __restrict__ midb,
    const float* __restrict__ rinfo, const ushort_t* __restrict__ Bg,
    float* __restrict__ out) {
  __shared__ ushort_t Bt[128][40];   // [d-row][2 experts x 16 j], +8 pad
  const int n = blockIdx.x, m = blockIdx.y, b = blockIdx.z;
  const int tid = threadIdx.x, w = tid >> 6, lane = tid & 63;
  const int lm = lane & 15, g = lane >> 4;

  const float4 ri = ((const float4*)rinfo)[b];
  const int i1 = (int)ri.x, i2 = (int)ri.y;
  const float w1 = ri.z, w2 = ri.w;

  // stage active-expert B slice, scaled by combine weight
#pragma unroll
  for (int c = 0; c < 2; ++c) {
    int ci = c * 256 + tid;
    int d = ci >> 2, sub = ci & 3;
    int e = (sub & 2) ? i2 : i1;
    float sc = (sub & 2) ? w2 : w1;
    bf16x8 bv = *(const bf16x8*)(Bg + ((size_t)(n * 128 + d)) * J_ + e * 16 + (sub & 1) * 8);
    bf16x8 bw;
#pragma unroll
    for (int i = 0; i < 8; ++i) bw[i] = (short)f2bf(bf2f((ushort_t)bv[i]) * sc);
    *(bf16x8*)&Bt[d][sub * 8] = bw;
  }

  // P fragment: raw bf16 mid loads of the active 32 j-columns
  const int srow = m * 64 + w * 16 + lm;
  const int jw = (g < 2) ? (i1 * 16 + g * 8) : (i2 * 16 + (g - 2) * 8);
  bf16x8 pf = *(const bf16x8*)&midb[((size_t)(b * S_ + srow)) * J_ + jw];
  __syncthreads();

  f32x4 acc[8] = {};
#pragma unroll
  for (int nn = 0; nn < 8; ++nn) {
    bf16x8 af = *(const bf16x8*)&Bt[nn * 16 + lm][g * 8];
    acc[nn] = __builtin_amdgcn_mfma_f32_16x16x32_bf16(af, pf, acc[nn], 0, 0, 0);
  }

  float* op = out + ((size_t)(b * S_ + srow)) * D_ + n * 128;
#pragma unroll
  for (int nn = 0; nn < 8; ++nn)
    *(f32x4*)&op[nn * 16 + g * 4] = acc[nn];
}

extern "C" void kernel_launch(void* const* d_in, const int* in_sizes, int n_in,
                              void* d_out, int out_size, void* d_ws, size_t ws_size,
                              hipStream_t stream) {
  const float* x    = (const float*)d_in[0];
  const float* gw   = (const float*)d_in[1];
  const float* tb   = (const float*)d_in[2];
  const float* mb   = (const float*)d_in[3];
  const float* lA   = (const float*)d_in[4];
  const float* lB   = (const float*)d_in[5];
  const int* task_p = (const int*)d_in[6];
  const int* mode_p = (const int*)d_in[7];
  float* out = (float*)d_out;
  char* ws = (char*)d_ws;
  ushort_t* midb  = (ushort_t*)ws;                 // 4,194,304 B
  ushort_t* Ag    = (ushort_t*)(ws + 4194304);     //   524,288 B
  ushort_t* Bg    = (ushort_t*)(ws + 4718592);     //   524,288 B
  float* lpart    = (float*)(ws + 5242880);        //    16,384 B
  float* rinfo    = (float*)(ws + 5259264);        //       128 B

  hipLaunchKernelGGL(k_prep, dim3(256), dim3(256), 0, stream, lA, lB, Ag, Bg);
  hipLaunchKernelGGL(k_mid, dim3(64, 8), dim3(256), 0, stream, x, Ag, gw, midb, lpart);
  hipLaunchKernelGGL(k_router, dim3(1), dim3(64), 0, stream,
                     lpart, tb, mb, task_p, mode_p, rinfo);
  hipLaunchKernelGGL(k_comb, dim3(16, 32, 8), dim3(256), 0, stream, midb, rinfo, Bg, out);
}